// Round 10
// baseline (133.800 us; speedup 1.0000x reference)
//
#include <hip/hip_runtime.h>
#include <hip/hip_bf16.h>
#include <math.h>

// ContrastiveLoss (NT-Xent), B=2048, D=1024, tau=0.5.
// loss = (1/n) sum_i [ logsumexp_{j!=i}(sim[i,j]/tau) - sim[i,partner]/tau ]
// sim = zn @ zn^T symmetric: upper-triangle 128x128 tiles (528 blocks), row+col
// LSE partials per tile, slot algebra race-free (see R7 note below).
// R9: k_lse was LATENCY-bound (MfmaUtil 10%, VALUBusy 16%, occ 11% — 74% idle;
// L2 traffic only 4.3 TB/s). Double-buffered staging with COUNTED vmcnt(8)
// (T3/T4): prefetch tile t+1 while computing t; loads stay in flight across
// the barrier instead of the __syncthreads() vmcnt(0) drain.
// R7: row-partials slot=2*tj+wc (>=2*ti), col-partials slot=2*ti+wr (<2*tj)
// -> all 64 slots per row written exactly once. pm/pl [row][slot] coalesced.

#define BB   2048
#define N2   4096
#define DIM  1024
#define TAUI 2.0f
#define EPSN 1e-8f

#define BM  128
#define BN  128
#define BKK 64
#define NK  (DIM / BKK)   // 16 K-steps
#define NP  64            // partial slots per row
#define NBLK 528          // 32*33/2 upper-triangle tiles

typedef __attribute__((ext_vector_type(4))) float f32x4;
typedef __attribute__((ext_vector_type(8))) short s16x8;

__device__ __forceinline__ void gll16(const void* g, void* l) {
    __builtin_amdgcn_global_load_lds(
        (const __attribute__((address_space(1))) void*)g,
        (__attribute__((address_space(3))) void*)l, 16, 0, 0);
}

// ------------- kernel 1: row norms + normalized bf16 cast -------------
__global__ __launch_bounds__(256) void k_prep(const float* __restrict__ zO,
                                              const float* __restrict__ zA,
                                              __hip_bfloat16* __restrict__ zb) {
    int row = blockIdx.x;
    const float* zr = (row < BB) ? (zA + (size_t)row * DIM)
                                 : (zO + (size_t)(row - BB) * DIM);
    int t = threadIdx.x;
    float4 v = *(const float4*)(zr + t * 4);
    float s = v.x * v.x + v.y * v.y + v.z * v.z + v.w * v.w;
    for (int m = 1; m < 64; m <<= 1) s += __shfl_xor(s, m);
    __shared__ float wsum[4];
    __shared__ float inv_s;
    int wv = t >> 6, ln = t & 63;
    if (ln == 0) wsum[wv] = s;
    __syncthreads();
    if (t == 0)
        inv_s = 1.0f / fmaxf(sqrtf(wsum[0] + wsum[1] + wsum[2] + wsum[3]), EPSN);
    __syncthreads();
    float inv = inv_s;
    __hip_bfloat16 h0 = __float2bfloat16(v.x * inv);
    __hip_bfloat16 h1 = __float2bfloat16(v.y * inv);
    __hip_bfloat16 h2 = __float2bfloat16(v.z * inv);
    __hip_bfloat16 h3 = __float2bfloat16(v.w * inv);
    ushort4 o;
    o.x = *(unsigned short*)&h0;
    o.y = *(unsigned short*)&h1;
    o.z = *(unsigned short*)&h2;
    o.w = *(unsigned short*)&h3;
    ((ushort4*)zb)[(size_t)row * (DIM / 4) + t] = o;
}

// ------------- kernel 2: MFMA GEMM (upper-triangle) + LSE partials -------------
__global__ __launch_bounds__(256) void k_lse(const __hip_bfloat16* __restrict__ zb,
                                             float* __restrict__ pm,
                                             float* __restrict__ pl,
                                             float* __restrict__ pos) {
    __shared__ __hip_bfloat16 As[2][BM * BKK];   // 2 x 16 KB (dbuf, gll dest)
    __shared__ __hip_bfloat16 Bs[2][BN * BKK];   // 2 x 16 KB

    // linear block id -> (ti, tj), ti <= tj; offset(t) = t*(65-t)/2
    int lin = blockIdx.x;
    int ti = (int)((65.0f - sqrtf(4225.0f - 8.0f * (float)lin)) * 0.5f);
    while ((ti + 1) * (65 - (ti + 1)) / 2 <= lin) ti++;
    while (ti * (65 - ti) / 2 > lin) ti--;
    int tj = ti + (lin - ti * (65 - ti) / 2);

    int ibase = ti * BM, jbase = tj * BN;
    int tid = threadIdx.x;
    int w = tid >> 6, l = tid & 63;
    int wr = w >> 1, wc = w & 1;          // 2x2 wave layout
    int rl = l & 15, kg = l >> 4;

    const __hip_bfloat16* Ag = zb + (size_t)ibase * DIM;
    const __hip_bfloat16* Bg = zb + (size_t)jbase * DIM;

    f32x4 acc[4][4];
#pragma unroll
    for (int m = 0; m < 4; m++)
#pragma unroll
        for (int n = 0; n < 4; n++) acc[m][n] = (f32x4){0.f, 0.f, 0.f, 0.f};

    int srow = l >> 3;            // 0..7 within segment (global row select)
    int scol = (l & 7) * 8;       // bf16 col offset (global)

    // 8 gll16 per thread per STAGE: segment s = wave-uniform LDS base,
    // per-lane global address (linear LDS dest rule, m104).
    auto stage = [&](int buf, int kt) {
#pragma unroll
        for (int s4 = 0; s4 < 4; s4++) {
            int s = w * 4 + s4;                  // segment 0..15 (8 rows each)
            int grow = 8 * s + srow;
            gll16(Ag + (size_t)grow * DIM + kt + scol, &As[buf][s * 512]);
            gll16(Bg + (size_t)grow * DIM + kt + scol, &Bs[buf][s * 512]);
        }
    };

    stage(0, 0);
    int cur = 0;
    for (int kt = 0; kt < NK; kt++) {
        if (kt + 1 < NK) {
            stage(cur ^ 1, (kt + 1) * BKK);      // prefetch next K-tile
            asm volatile("s_waitcnt vmcnt(8)" ::: "memory");   // cur's 8 loads done
        } else {
            asm volatile("s_waitcnt vmcnt(0)" ::: "memory");
        }
        __builtin_amdgcn_sched_barrier(0);
        __builtin_amdgcn_s_barrier();            // all waves: buf[cur] resident

#pragma unroll
        for (int kk = 0; kk < 2; kk++) {
            s16x8 a[4], b[4];
#pragma unroll
            for (int m = 0; m < 4; m++)
                a[m] = *(const s16x8*)&As[cur][(wr * 64 + m * 16 + rl) * BKK + kk * 32 + kg * 8];
#pragma unroll
            for (int n = 0; n < 4; n++)
                b[n] = *(const s16x8*)&Bs[cur][(wc * 64 + n * 16 + rl) * BKK + kk * 32 + kg * 8];
#pragma unroll
            for (int m = 0; m < 4; m++)
#pragma unroll
                for (int n = 0; n < 4; n++)
                    acc[m][n] = __builtin_amdgcn_mfma_f32_16x16x32_bf16(
                        a[m], b[n], acc[m][n], 0, 0, 0);
        }

        asm volatile("s_waitcnt lgkmcnt(0)" ::: "memory");  // ds_reads retired
        __builtin_amdgcn_sched_barrier(0);
        __builtin_amdgcn_s_barrier();            // buf[cur] free for next stage
        cur ^= 1;
    }

    // ---- row-path epilogue: per-row (max, sumexp) over this tile's 64 cols ----
    // C/D mapping (m89): col = lane&15, row = (lane>>4)*4 + reg
    int rowbase = ibase + wr * 64;
    int colbase = jbase + wc * 64;
    int slot = tj * 2 + wc;               // row-partial slot
#pragma unroll
    for (int m = 0; m < 4; m++) {
#pragma unroll
        for (int r = 0; r < 4; r++) {
            int ig = rowbase + m * 16 + kg * 4 + r;
            int pp = (ig + BB) & (N2 - 1);
            float v[4];
            float rmax = -1e30f;
#pragma unroll
            for (int n = 0; n < 4; n++) {
                int jg = colbase + n * 16 + rl;
                float val = acc[m][n][r] * TAUI;
                if (jg == pp) { pos[ig] = val; pos[jg] = val; }  // sim symmetric
                if (jg == ig) val = -1e30f;       // exclude diagonal
                v[n] = val;
                rmax = fmaxf(rmax, val);
            }
#pragma unroll
            for (int mk = 1; mk < 16; mk <<= 1)
                rmax = fmaxf(rmax, __shfl_xor(rmax, mk));
            float ssum = 0.f;
#pragma unroll
            for (int n = 0; n < 4; n++) ssum += __expf(v[n] - rmax);
#pragma unroll
            for (int mk = 1; mk < 16; mk <<= 1) ssum += __shfl_xor(ssum, mk);
            if (rl == 0) {
                pm[(size_t)ig * NP + slot] = rmax;
                pl[(size_t)ig * NP + slot] = ssum;
            }
        }
    }

    // ---- col-path epilogue (off-diagonal only): partials for tile tj's rows ----
    if (ti != tj) {
        int slot2 = ti * 2 + wr;
#pragma unroll
        for (int n = 0; n < 4; n++) {
            float cmax = -1e30f;
#pragma unroll
            for (int m = 0; m < 4; m++)
#pragma unroll
                for (int r = 0; r < 4; r++)
                    cmax = fmaxf(cmax, acc[m][n][r] * TAUI);
            cmax = fmaxf(cmax, __shfl_xor(cmax, 16));
            cmax = fmaxf(cmax, __shfl_xor(cmax, 32));
            float cs = 0.f;
#pragma unroll
            for (int m = 0; m < 4; m++)
#pragma unroll
                for (int r = 0; r < 4; r++)
                    cs += __expf(acc[m][n][r] * TAUI - cmax);
            cs += __shfl_xor(cs, 16);
            cs += __shfl_xor(cs, 32);
            if (l < 16) {                        // kg==0 lanes
                int jg = colbase + n * 16 + rl;
                pm[(size_t)jg * NP + slot2] = cmax;
                pl[(size_t)jg * NP + slot2] = cs;
            }
        }
    }
}

// ------------- kernel 3: combine partials -> loss -------------
__global__ __launch_bounds__(256) void k_combine(const float* __restrict__ pm,
                                                 const float* __restrict__ pl,
                                                 const float* __restrict__ pos,
                                                 float* __restrict__ out) {
    int row = blockIdx.x * 256 + threadIdx.x;
    const float* P = pm + (size_t)row * NP;    // contiguous 64 floats
    const float* L = pl + (size_t)row * NP;
    float M = -1e30f;
#pragma unroll
    for (int c = 0; c < NP; c++) M = fmaxf(M, P[c]);
    float S = 0.f;
#pragma unroll
    for (int c = 0; c < NP; c++) S += L[c] * __expf(P[c] - M);
    float v = M + __logf(S) - pos[row];
    for (int mk = 1; mk < 64; mk <<= 1) v += __shfl_xor(v, mk);
    __shared__ float wsum[4];
    int wv = threadIdx.x >> 6, ln = threadIdx.x & 63;
    if (ln == 0) wsum[wv] = v;
    __syncthreads();
    if (threadIdx.x == 0)
        atomicAdd(out, (wsum[0] + wsum[1] + wsum[2] + wsum[3]) * (1.0f / (float)N2));
}

extern "C" void kernel_launch(void* const* d_in, const int* in_sizes, int n_in,
                              void* d_out, int out_size, void* d_ws, size_t ws_size,
                              hipStream_t stream) {
    const float* zO = (const float*)d_in[0];   // z_orig    -> rows B..2B-1
    const float* zA = (const float*)d_in[1];   // z_augment -> rows 0..B-1
    float* out = (float*)d_out;

    __hip_bfloat16* zb = (__hip_bfloat16*)d_ws;          // 4096*1024 bf16 = 8 MB
    float* pm  = (float*)((char*)d_ws + (size_t)N2 * DIM * 2);   // [4096][64]
    float* pl  = pm + (size_t)N2 * NP;                            // [4096][64]
    float* pos = pl + (size_t)N2 * NP;                            // 4096

    hipMemsetAsync(out, 0, sizeof(float), stream);
    k_prep<<<N2, 256, 0, stream>>>(zO, zA, zb);
    k_lse<<<NBLK, 256, 0, stream>>>(zb, pm, pl, pos);
    k_combine<<<N2 / 256, 256, 0, stream>>>(pm, pl, pos, out);
}

// Round 14
// 125.914 us; speedup vs baseline: 1.0626x; 1.0626x over previous
//
#include <hip/hip_runtime.h>
#include <hip/hip_bf16.h>
#include <math.h>

// ContrastiveLoss (NT-Xent), B=2048, D=1024, tau=0.5.
// loss = (1/n) sum_i [ logsumexp_{j!=i}(sim[i,j]/tau) - sim[i,partner]/tau ]
// sim = zn @ zn^T symmetric: upper-triangle 128x128 tiles (528 blocks).
// R11 post-mortem: K-split was MATHEMATICALLY INVALID for LSE (exp of partial
// dots; exp(h1)+exp(h2) != exp(h1+h2) -> S doubled -> err = log 2). Full K
// per block restored.
// R12: fix starvation with 8 WAVES/block (512 thr, 2x4 wave grid, 64x32 per
// wave): 2.06 blk/CU x 8 = 16.5 waves/CU (= R7's TLP) at half R7's staging
// volume. LDS 32KB single-buffer. Swizzled staging (both-sides, rule 21):
// phys chunk cx of row r holds global chunk cx^(r&7); read chunk
// (kk*4+kg)^(rl&7) -> ~8-way aliasing (down from 16-way; 8 is the floor for
// 64 rows x 8 chunks with this fragment layout).
// Slots: row path 4*tj+wc (in [4t,128)), col path 2*ti+wr (in [0,2t));
// gap [2t,4t) covered by zeroed pm/pl (contributes 0 to S). NP=128.

#define BB   2048
#define N2   4096
#define DIM  1024
#define TAUI 2.0f
#define EPSN 1e-8f

#define BM  128
#define BN  128
#define BKK 64
#define NK  (DIM / BKK)   // 16 K-steps, full K per block
#define NP  128           // partial slots per row
#define NTRI 528          // 32*33/2 upper-triangle tiles

typedef __attribute__((ext_vector_type(4))) float f32x4;
typedef __attribute__((ext_vector_type(8))) short s16x8;

__device__ __forceinline__ void gll16(const void* g, void* l) {
    __builtin_amdgcn_global_load_lds(
        (const __attribute__((address_space(1))) void*)g,
        (__attribute__((address_space(3))) void*)l, 16, 0, 0);
}

// ------------- kernel 1: row norms + normalized bf16 cast (1 wave/row) -------
__global__ __launch_bounds__(256) void k_prep(const float* __restrict__ zO,
                                              const float* __restrict__ zA,
                                              __hip_bfloat16* __restrict__ zb) {
    int row = (blockIdx.x * 256 + threadIdx.x) >> 6;   // 4096 waves
    int lane = threadIdx.x & 63;
    const float* zr = (row < BB) ? (zA + (size_t)row * DIM)
                                 : (zO + (size_t)(row - BB) * DIM);
    float4 v[4];
    float s = 0.f;
#pragma unroll
    for (int q = 0; q < 4; q++) {
        v[q] = *(const float4*)(zr + q * 256 + lane * 4);
        s += v[q].x * v[q].x + v[q].y * v[q].y + v[q].z * v[q].z + v[q].w * v[q].w;
    }
#pragma unroll
    for (int m = 1; m < 64; m <<= 1) s += __shfl_xor(s, m);
    float inv = 1.0f / fmaxf(sqrtf(s), EPSN);
#pragma unroll
    for (int q = 0; q < 4; q++) {
        __hip_bfloat16 h0 = __float2bfloat16(v[q].x * inv);
        __hip_bfloat16 h1 = __float2bfloat16(v[q].y * inv);
        __hip_bfloat16 h2 = __float2bfloat16(v[q].z * inv);
        __hip_bfloat16 h3 = __float2bfloat16(v[q].w * inv);
        ushort4 o;
        o.x = *(unsigned short*)&h0;
        o.y = *(unsigned short*)&h1;
        o.z = *(unsigned short*)&h2;
        o.w = *(unsigned short*)&h3;
        ((ushort4*)zb)[(size_t)row * 256 + q * 64 + lane] = o;
    }
}

// ------------- kernel 2: 8-wave MFMA GEMM (upper-triangle) + LSE partials ----
__global__ __launch_bounds__(512) void k_lse(const __hip_bfloat16* __restrict__ zb,
                                             float* __restrict__ pm,
                                             float* __restrict__ pl,
                                             float* __restrict__ pos) {
    __shared__ __hip_bfloat16 As[BM * BKK];   // 16 KB, linear (gll dest)
    __shared__ __hip_bfloat16 Bs[BN * BKK];   // 16 KB

    // linear block id -> (ti, tj), ti <= tj; offset(t) = t*(65-t)/2
    int lin = blockIdx.x;
    int ti = (int)((65.0f - sqrtf(4225.0f - 8.0f * (float)lin)) * 0.5f);
    while ((ti + 1) * (65 - (ti + 1)) / 2 <= lin) ti++;
    while (ti * (65 - ti) / 2 > lin) ti--;
    int tj = ti + (lin - ti * (65 - ti) / 2);

    int ibase = ti * BM, jbase = tj * BN;
    int tid = threadIdx.x;
    int w = tid >> 6, l = tid & 63;
    int wr = w >> 2, wc = w & 3;          // 2x4 wave layout: 64x32 per wave
    int rl = l & 15, kg = l >> 4;
    int cx = l & 7;                       // lane's phys 16B chunk in its row
    int srow = l >> 3;                    // 0..7: row within 8-row segment
    int scol = ((cx ^ srow) * 8);         // pre-swizzled source col (bf16)

    const __hip_bfloat16* Ag = zb + (size_t)ibase * DIM;
    const __hip_bfloat16* Bg = zb + (size_t)jbase * DIM;

    f32x4 acc[4][2];
#pragma unroll
    for (int m = 0; m < 4; m++)
#pragma unroll
        for (int n = 0; n < 2; n++) acc[m][n] = (f32x4){0.f, 0.f, 0.f, 0.f};

    for (int kt = 0; kt < DIM; kt += BKK) {
        __syncthreads();
        // 8 waves x 2 segments each (A and B): 4 gll16/thread
#pragma unroll
        for (int s4 = 0; s4 < 2; s4++) {
            int s = w * 2 + s4;                  // segment 0..15 (8 rows each)
            int grow = 8 * s + srow;
            gll16(Ag + (size_t)grow * DIM + kt + scol, &As[s * 512]);
            gll16(Bg + (size_t)grow * DIM + kt + scol, &Bs[s * 512]);
        }
        __syncthreads();

#pragma unroll
        for (int kk = 0; kk < 2; kk++) {
            s16x8 a[4], b[2];
            int ch = (((kk * 4 + kg) ^ (rl & 7)) * 8);   // swizzled read chunk
#pragma unroll
            for (int m = 0; m < 4; m++)
                a[m] = *(const s16x8*)&As[(wr * 64 + m * 16 + rl) * BKK + ch];
#pragma unroll
            for (int n = 0; n < 2; n++)
                b[n] = *(const s16x8*)&Bs[(wc * 32 + n * 16 + rl) * BKK + ch];
#pragma unroll
            for (int m = 0; m < 4; m++)
#pragma unroll
                for (int n = 0; n < 2; n++)
                    acc[m][n] = __builtin_amdgcn_mfma_f32_16x16x32_bf16(
                        a[m], b[n], acc[m][n], 0, 0, 0);
        }
    }

    // ---- row-path epilogue: per-row (max, sumexp) over this wave's 32 cols ----
    // C/D mapping (m89): col = lane&15, row = (lane>>4)*4 + reg
    int rowbase = ibase + wr * 64;
    int colbase = jbase + wc * 32;
    int slot = tj * 4 + wc;               // row-partial slot
#pragma unroll
    for (int m = 0; m < 4; m++) {
#pragma unroll
        for (int r = 0; r < 4; r++) {
            int ig = rowbase + m * 16 + kg * 4 + r;
            int pp = (ig + BB) & (N2 - 1);
            float v[2];
            float rmax = -1e30f;
#pragma unroll
            for (int n = 0; n < 2; n++) {
                int jg = colbase + n * 16 + rl;
                float val = acc[m][n][r] * TAUI;
                if (jg == pp) { pos[ig] = val; pos[jg] = val; }  // sim symmetric
                if (jg == ig) val = -1e30f;       // exclude diagonal
                v[n] = val;
                rmax = fmaxf(rmax, val);
            }
#pragma unroll
            for (int mk = 1; mk < 16; mk <<= 1)
                rmax = fmaxf(rmax, __shfl_xor(rmax, mk));
            float ssum = 0.f;
#pragma unroll
            for (int n = 0; n < 2; n++) ssum += __expf(v[n] - rmax);
#pragma unroll
            for (int mk = 1; mk < 16; mk <<= 1) ssum += __shfl_xor(ssum, mk);
            if (rl == 0) {
                pm[(size_t)ig * NP + slot] = rmax;
                pl[(size_t)ig * NP + slot] = ssum;
            }
        }
    }

    // ---- col-path epilogue (off-diagonal only): partials for tile tj's rows
    // over this wave's 64 rows (wr half) ----
    if (ti != tj) {
        int slot2 = ti * 2 + wr;
#pragma unroll
        for (int n = 0; n < 2; n++) {
            float cmax = -1e30f;
#pragma unroll
            for (int m = 0; m < 4; m++)
#pragma unroll
                for (int r = 0; r < 4; r++)
                    cmax = fmaxf(cmax, acc[m][n][r] * TAUI);
            cmax = fmaxf(cmax, __shfl_xor(cmax, 16));
            cmax = fmaxf(cmax, __shfl_xor(cmax, 32));
            float cs = 0.f;
#pragma unroll
            for (int m = 0; m < 4; m++)
#pragma unroll
                for (int r = 0; r < 4; r++)
                    cs += __expf(acc[m][n][r] * TAUI - cmax);
            cs += __shfl_xor(cs, 16);
            cs += __shfl_xor(cs, 32);
            if (l < 16) {                        // kg==0 lanes
                int jg = colbase + n * 16 + rl;
                pm[(size_t)jg * NP + slot2] = cmax;
                pl[(size_t)jg * NP + slot2] = cs;
            }
        }
    }
}

// ------------- kernel 3: combine partials -> loss (online, 1 thread/row) ----
__global__ __launch_bounds__(256) void k_combine(const float* __restrict__ pm,
                                                 const float* __restrict__ pl,
                                                 const float* __restrict__ pos,
                                                 float* __restrict__ out) {
    int row = blockIdx.x * 256 + threadIdx.x;
    const float4* P4 = (const float4*)(pm + (size_t)row * NP);   // 32 vec4
    const float4* L4 = (const float4*)(pl + (size_t)row * NP);
    float M = -1e30f, S = 0.f;
#pragma unroll
    for (int c = 0; c < NP / 4; c++) {
        float4 p = P4[c], q = L4[c];
        float nm = fmaxf(M, fmaxf(fmaxf(p.x, p.y), fmaxf(p.z, p.w)));
        S = S * __expf(M - nm)
          + q.x * __expf(p.x - nm) + q.y * __expf(p.y - nm)
          + q.z * __expf(p.z - nm) + q.w * __expf(p.w - nm);
        M = nm;
    }
    float v = M + __logf(S) - pos[row];
#pragma unroll
    for (int mk = 1; mk < 64; mk <<= 1) v += __shfl_xor(v, mk);
    __shared__ float wsum[4];
    int wv = threadIdx.x >> 6, ln = threadIdx.x & 63;
    if (ln == 0) wsum[wv] = v;
    __syncthreads();
    if (threadIdx.x == 0)
        atomicAdd(out, (wsum[0] + wsum[1] + wsum[2] + wsum[3]) * (1.0f / (float)N2));
}

extern "C" void kernel_launch(void* const* d_in, const int* in_sizes, int n_in,
                              void* d_out, int out_size, void* d_ws, size_t ws_size,
                              hipStream_t stream) {
    const float* zO = (const float*)d_in[0];   // z_orig    -> rows B..2B-1
    const float* zA = (const float*)d_in[1];   // z_augment -> rows 0..B-1
    float* out = (float*)d_out;

    __hip_bfloat16* zb = (__hip_bfloat16*)d_ws;          // 4096*1024 bf16 = 8 MB
    float* pm  = (float*)((char*)d_ws + (size_t)N2 * DIM * 2);   // [4096][128]
    float* pl  = pm + (size_t)N2 * NP;                            // [4096][128]
    float* pos = pl + (size_t)N2 * NP;                            // 4096

    hipMemsetAsync(out, 0, sizeof(float), stream);
    hipMemsetAsync(pm, 0, (size_t)N2 * NP * 2 * sizeof(float), stream); // pm+pl
    k_prep<<<N2 / 4, 256, 0, stream>>>(zO, zA, zb);
    k_lse<<<NTRI, 512, 0, stream>>>(zb, pm, pl, pos);
    k_combine<<<N2 / 256, 256, 0, stream>>>(pm, pl, pos, out);
}

// Round 15
// 119.344 us; speedup vs baseline: 1.1211x; 1.0550x over previous
//
#include <hip/hip_runtime.h>
#include <hip/hip_bf16.h>
#include <math.h>

// ContrastiveLoss (NT-Xent), B=2048, D=1024, tau=0.5.
// loss = (1/n) sum_i [ logsumexp_{j!=i}(sim[i,j]/tau) - sim[i,partner]/tau ]
// sim = zn @ zn^T symmetric: upper-triangle 128x128 tiles, M-SPLIT x2.
// R14 post-mortem: 50.5us, utils ~30%, conflicts 0 (swizzle works), latency-
// bound. Cross-round signal: INDEPENDENT blocks/CU drive overlap (R7 4blk >
// R9 2blk; R10 in-block prefetch null). R15: M-split -> 1056 blocks of
// 64x128 (256thr/4 waves of 64x32), 4.1 independent blocks/CU @ 24KB LDS.
// Also: k_prep zeros pm||pl+out -> both memset dispatches dropped (launch
// overhead was part of the 75us non-GEMM time).
// Slots: row path 4*tj+wc (in [4t,128)); col path 2*ti+mh (in [0,2t));
// gap [2t,4t) covered by zeroed pm/pl (contributes 0 to S). NP=128.
// Swizzle (both-sides, rule 21): phys chunk cx of row r holds global chunk
// cx^(r&7); read chunk (kk*4+kg)^(rl&7).

#define BB   2048
#define N2   4096
#define DIM  1024
#define TAUI 2.0f
#define EPSN 1e-8f

#define BMH 64            // A-rows per block (M-split half)
#define BN  128
#define BKK 64
#define NP  128           // partial slots per row
#define NTRI 528          // 32*33/2 upper-triangle tiles

typedef __attribute__((ext_vector_type(4))) float f32x4;
typedef __attribute__((ext_vector_type(8))) short s16x8;

__device__ __forceinline__ void gll16(const void* g, void* l) {
    __builtin_amdgcn_global_load_lds(
        (const __attribute__((address_space(1))) void*)g,
        (__attribute__((address_space(3))) void*)l, 16, 0, 0);
}

// -------- kernel 1: row norms + bf16 cast (1 wave/row) + ws zero-init --------
__global__ __launch_bounds__(256) void k_prep(const float* __restrict__ zO,
                                              const float* __restrict__ zA,
                                              __hip_bfloat16* __restrict__ zb,
                                              float* __restrict__ pmpl,
                                              float* __restrict__ out) {
    // zero pm||pl (2*N2*NP floats = 262144 float4, == grid*block exactly)
    int gtid = blockIdx.x * 256 + threadIdx.x;
    ((float4*)pmpl)[gtid] = (float4){0.f, 0.f, 0.f, 0.f};
    if (gtid == 0) out[0] = 0.f;

    int row = gtid >> 6;                  // 4096 waves, 1 row each
    int lane = threadIdx.x & 63;
    const float* zr = (row < BB) ? (zA + (size_t)row * DIM)
                                 : (zO + (size_t)(row - BB) * DIM);
    float4 v[4];
    float s = 0.f;
#pragma unroll
    for (int q = 0; q < 4; q++) {
        v[q] = *(const float4*)(zr + q * 256 + lane * 4);
        s += v[q].x * v[q].x + v[q].y * v[q].y + v[q].z * v[q].z + v[q].w * v[q].w;
    }
#pragma unroll
    for (int m = 1; m < 64; m <<= 1) s += __shfl_xor(s, m);
    float inv = 1.0f / fmaxf(sqrtf(s), EPSN);
#pragma unroll
    for (int q = 0; q < 4; q++) {
        __hip_bfloat16 h0 = __float2bfloat16(v[q].x * inv);
        __hip_bfloat16 h1 = __float2bfloat16(v[q].y * inv);
        __hip_bfloat16 h2 = __float2bfloat16(v[q].z * inv);
        __hip_bfloat16 h3 = __float2bfloat16(v[q].w * inv);
        ushort4 o;
        o.x = *(unsigned short*)&h0;
        o.y = *(unsigned short*)&h1;
        o.z = *(unsigned short*)&h2;
        o.w = *(unsigned short*)&h3;
        ((ushort4*)zb)[(size_t)row * 256 + q * 64 + lane] = o;
    }
}

// ---- kernel 2: 4-wave 64x128 MFMA GEMM (upper-triangle, M-split) + LSE ----
__global__ __launch_bounds__(256) void k_lse(const __hip_bfloat16* __restrict__ zb,
                                             float* __restrict__ pm,
                                             float* __restrict__ pl,
                                             float* __restrict__ pos) {
    __shared__ __hip_bfloat16 As[BMH * BKK];  // 8 KB, linear (gll dest)
    __shared__ __hip_bfloat16 Bs[BN * BKK];   // 16 KB

    // linear block id -> (ti, tj), ti <= tj; offset(t) = t*(65-t)/2
    int lin = blockIdx.x;
    int mh = blockIdx.y;                  // which 64-row half of the A-tile
    int ti = (int)((65.0f - sqrtf(4225.0f - 8.0f * (float)lin)) * 0.5f);
    while ((ti + 1) * (65 - (ti + 1)) / 2 <= lin) ti++;
    while (ti * (65 - ti) / 2 > lin) ti--;
    int tj = ti + (lin - ti * (65 - ti) / 2);

    int ibase = ti * 128 + mh * BMH;      // this block's 64 A-rows
    int jbase = tj * 128;
    int tid = threadIdx.x;
    int w = tid >> 6, l = tid & 63;       // 4 waves; wave w = cols w*32..+32
    int wc = w;
    int rl = l & 15, kg = l >> 4;
    int cx = l & 7;                       // lane's phys 16B chunk in its row
    int srow = l >> 3;                    // 0..7: row within 8-row segment
    int scol = ((cx ^ srow) * 8);         // pre-swizzled source col (bf16)

    const __hip_bfloat16* Ag = zb + (size_t)ibase * DIM;
    const __hip_bfloat16* Bg = zb + (size_t)jbase * DIM;

    f32x4 acc[4][2];
#pragma unroll
    for (int m = 0; m < 4; m++)
#pragma unroll
        for (int n = 0; n < 2; n++) acc[m][n] = (f32x4){0.f, 0.f, 0.f, 0.f};

    for (int kt = 0; kt < DIM; kt += BKK) {
        __syncthreads();
        // A: 8 segments of 8 rows -> wave w takes segs 2w,2w+1 (2 gll16/thread)
#pragma unroll
        for (int s4 = 0; s4 < 2; s4++) {
            int s = w * 2 + s4;
            int grow = 8 * s + srow;
            gll16(Ag + (size_t)grow * DIM + kt + scol, &As[s * 512]);
        }
        // B: 16 segments -> wave w takes segs 4w..4w+3 (4 gll16/thread)
#pragma unroll
        for (int s4 = 0; s4 < 4; s4++) {
            int s = w * 4 + s4;
            int grow = 8 * s + srow;
            gll16(Bg + (size_t)grow * DIM + kt + scol, &Bs[s * 512]);
        }
        __syncthreads();

#pragma unroll
        for (int kk = 0; kk < 2; kk++) {
            s16x8 a[4], b[2];
            int ch = (((kk * 4 + kg) ^ (rl & 7)) * 8);   // swizzled read chunk
#pragma unroll
            for (int m = 0; m < 4; m++)
                a[m] = *(const s16x8*)&As[(m * 16 + rl) * BKK + ch];
#pragma unroll
            for (int n = 0; n < 2; n++)
                b[n] = *(const s16x8*)&Bs[(wc * 32 + n * 16 + rl) * BKK + ch];
#pragma unroll
            for (int m = 0; m < 4; m++)
#pragma unroll
                for (int n = 0; n < 2; n++)
                    acc[m][n] = __builtin_amdgcn_mfma_f32_16x16x32_bf16(
                        a[m], b[n], acc[m][n], 0, 0, 0);
        }
    }

    // ---- row-path epilogue: per-row (max, sumexp) over this wave's 32 cols ----
    // C/D mapping (m89): col = lane&15, row = (lane>>4)*4 + reg
    int colbase = jbase + wc * 32;
    int slot = tj * 4 + wc;               // row-partial slot
#pragma unroll
    for (int m = 0; m < 4; m++) {
#pragma unroll
        for (int r = 0; r < 4; r++) {
            int ig = ibase + m * 16 + kg * 4 + r;
            int pp = (ig + BB) & (N2 - 1);
            float v[2];
            float rmax = -1e30f;
#pragma unroll
            for (int n = 0; n < 2; n++) {
                int jg = colbase + n * 16 + rl;
                float val = acc[m][n][r] * TAUI;
                if (jg == pp) { pos[ig] = val; pos[jg] = val; }  // sim symmetric
                if (jg == ig) val = -1e30f;       // exclude diagonal
                v[n] = val;
                rmax = fmaxf(rmax, val);
            }
#pragma unroll
            for (int mk = 1; mk < 16; mk <<= 1)
                rmax = fmaxf(rmax, __shfl_xor(rmax, mk));
            float ssum = 0.f;
#pragma unroll
            for (int n = 0; n < 2; n++) ssum += __expf(v[n] - rmax);
#pragma unroll
            for (int mk = 1; mk < 16; mk <<= 1) ssum += __shfl_xor(ssum, mk);
            if (rl == 0) {
                pm[(size_t)ig * NP + slot] = rmax;
                pl[(size_t)ig * NP + slot] = ssum;
            }
        }
    }

    // ---- col-path epilogue (off-diagonal only): partials for tile tj's rows
    // over this block's 64 A-rows ----
    if (ti != tj) {
        int slot2 = ti * 2 + mh;
#pragma unroll
        for (int n = 0; n < 2; n++) {
            float cmax = -1e30f;
#pragma unroll
            for (int m = 0; m < 4; m++)
#pragma unroll
                for (int r = 0; r < 4; r++)
                    cmax = fmaxf(cmax, acc[m][n][r] * TAUI);
            cmax = fmaxf(cmax, __shfl_xor(cmax, 16));
            cmax = fmaxf(cmax, __shfl_xor(cmax, 32));
            float cs = 0.f;
#pragma unroll
            for (int m = 0; m < 4; m++)
#pragma unroll
                for (int r = 0; r < 4; r++)
                    cs += __expf(acc[m][n][r] * TAUI - cmax);
            cs += __shfl_xor(cs, 16);
            cs += __shfl_xor(cs, 32);
            if (l < 16) {                        // kg==0 lanes
                int jg = colbase + n * 16 + rl;
                pm[(size_t)jg * NP + slot2] = cmax;
                pl[(size_t)jg * NP + slot2] = cs;
            }
        }
    }
}

// ------------- kernel 3: combine partials -> loss (online, 1 thread/row) ----
__global__ __launch_bounds__(256) void k_combine(const float* __restrict__ pm,
                                                 const float* __restrict__ pl,
                                                 const float* __restrict__ pos,
                                                 float* __restrict__ out) {
    int row = blockIdx.x * 256 + threadIdx.x;
    const float4* P4 = (const float4*)(pm + (size_t)row * NP);   // 32 vec4
    const float4* L4 = (const float4*)(pl + (size_t)row * NP);
    float M = -1e30f, S = 0.f;
#pragma unroll
    for (int c = 0; c < NP / 4; c++) {
        float4 p = P4[c], q = L4[c];
        float nm = fmaxf(M, fmaxf(fmaxf(p.x, p.y), fmaxf(p.z, p.w)));
        S = S * __expf(M - nm)
          + q.x * __expf(p.x - nm) + q.y * __expf(p.y - nm)
          + q.z * __expf(p.z - nm) + q.w * __expf(p.w - nm);
        M = nm;
    }
    float v = M + __logf(S) - pos[row];
#pragma unroll
    for (int mk = 1; mk < 64; mk <<= 1) v += __shfl_xor(v, mk);
    __shared__ float wsum[4];
    int wv = threadIdx.x >> 6, ln = threadIdx.x & 63;
    if (ln == 0) wsum[wv] = v;
    __syncthreads();
    if (threadIdx.x == 0)
        atomicAdd(out, (wsum[0] + wsum[1] + wsum[2] + wsum[3]) * (1.0f / (float)N2));
}

extern "C" void kernel_launch(void* const* d_in, const int* in_sizes, int n_in,
                              void* d_out, int out_size, void* d_ws, size_t ws_size,
                              hipStream_t stream) {
    const float* zO = (const float*)d_in[0];   // z_orig    -> rows B..2B-1
    const float* zA = (const float*)d_in[1];   // z_augment -> rows 0..B-1
    float* out = (float*)d_out;

    __hip_bfloat16* zb = (__hip_bfloat16*)d_ws;          // 4096*1024 bf16 = 8 MB
    float* pm  = (float*)((char*)d_ws + (size_t)N2 * DIM * 2);   // [4096][128]
    float* pl  = pm + (size_t)N2 * NP;                            // [4096][128]
    float* pos = pl + (size_t)N2 * NP;                            // 4096

    k_prep<<<N2 / 4, 256, 0, stream>>>(zO, zA, zb, pm, out);  // also zeros pm/pl/out
    k_lse<<<dim3(NTRI, 2), 256, 0, stream>>>(zb, pm, pl, pos);
    k_combine<<<N2 / 256, 256, 0, stream>>>(pm, pl, pos, out);
}